// Round 5
// baseline (384.004 us; speedup 1.0000x reference)
//
#include <hip/hip_runtime.h>
#include <hip/hip_bf16.h>
#include <stdint.h>

typedef __bf16 bf16_t;
typedef __bf16 bf16x8 __attribute__((ext_vector_type(8)));
typedef float f32x4 __attribute__((ext_vector_type(4)));
typedef _Float16 f16x8v __attribute__((ext_vector_type(8)));
typedef _Float16 f16x4v __attribute__((ext_vector_type(4)));

#define LOG2E 1.44269504088896f

// async global->LDS, 16B per lane. LDS dest must be wave-uniform base; data
// lands at base + lane*16.
__device__ __forceinline__ void load_lds16(const void* g, void* l) {
  __builtin_amdgcn_global_load_lds(
      (__attribute__((address_space(1))) unsigned int*)(uintptr_t)(g),
      (__attribute__((address_space(3))) unsigned int*)(l),
      16, 0, 0);
}

// pack 4 floats -> f16x4v via v_cvt_pkrtz_f16_f32 pairs (builtin returns
// __fp16 vectors; bit-cast to the _Float16 vector type used by MFMA operands)
__device__ __forceinline__ f16x4v pack4_f16(float a, float b, float c, float d) {
  const __fp16 __attribute__((ext_vector_type(2))) lo = __builtin_amdgcn_cvt_pkrtz(a, b);
  const __fp16 __attribute__((ext_vector_type(2))) hi = __builtin_amdgcn_cvt_pkrtz(c, d);
  return __builtin_bit_cast(f16x4v, __builtin_shufflevector(lo, hi, 0, 1, 2, 3));
}

// ---------------- LayerNorm over rows of 2048 fp32 ----------------
__global__ __launch_bounds__(256) void ln_kernel(
    const float* __restrict__ in, const float* __restrict__ gamma,
    bf16_t* __restrict__ out_bf, float* __restrict__ out_f)
{
  const int row = blockIdx.x;
  const int t = threadIdx.x;
  const float* x = in + (size_t)row * 2048;
  float4 a = ((const float4*)x)[t];
  float4 b = ((const float4*)x)[t + 256];
  float v[8] = {a.x, a.y, a.z, a.w, b.x, b.y, b.z, b.w};
  float s = 0.f, q = 0.f;
#pragma unroll
  for (int i = 0; i < 8; ++i) { s += v[i]; q += v[i] * v[i]; }
#pragma unroll
  for (int off = 1; off < 64; off <<= 1) {
    s += __shfl_xor(s, off, 64);
    q += __shfl_xor(q, off, 64);
  }
  __shared__ float red[4][2];
  if ((t & 63) == 0) { red[t >> 6][0] = s; red[t >> 6][1] = q; }
  __syncthreads();
  s = red[0][0] + red[1][0] + red[2][0] + red[3][0];
  q = red[0][1] + red[1][1] + red[2][1] + red[3][1];
  const float mean = s * (1.0f / 2048.0f);
  const float var = q * (1.0f / 2048.0f) - mean * mean;
  const float inv = rsqrtf(var + 1e-6f);
  float4 ga = ((const float4*)gamma)[t];
  float4 gb = ((const float4*)gamma)[t + 256];
  float g[8] = {ga.x, ga.y, ga.z, ga.w, gb.x, gb.y, gb.z, gb.w};
  float y[8];
#pragma unroll
  for (int i = 0; i < 8; ++i) y[i] = (v[i] - mean) * inv * g[i];
  if (out_bf) {
    alignas(16) bf16_t tb[8];
#pragma unroll
    for (int i = 0; i < 8; ++i) tb[i] = (bf16_t)y[i];
    bf16_t* o = out_bf + (size_t)row * 2048;
    *(uint2*)(o + t * 4) = *(const uint2*)(tb);
    *(uint2*)(o + (t + 256) * 4) = *(const uint2*)(tb + 4);
  } else {
    float* o = out_f + (size_t)row * 2048;
    ((float4*)o)[t] = make_float4(y[0], y[1], y[2], y[3]);
    ((float4*)o)[t + 256] = make_float4(y[4], y[5], y[6], y[7]);
  }
}

// ------------- transpose + cast: out[c][r] = (OT)in[r][c] -------------
// grid: (C/32, R/32, NB), block (32,8)
template <typename IT, typename OT>
__global__ __launch_bounds__(256) void transpose_cast(
    const IT* __restrict__ in, OT* __restrict__ out,
    int in_stride, int out_stride, long in_bstride, long out_bstride)
{
  const int bz = blockIdx.z;
  const IT* ib = in + (size_t)bz * in_bstride;
  OT* ob = out + (size_t)bz * out_bstride;
  const int c0 = blockIdx.x * 32, r0 = blockIdx.y * 32;
  const int tx = threadIdx.x, ty = threadIdx.y;
  __shared__ float tile[32][33];
#pragma unroll
  for (int i = 0; i < 4; ++i)
    tile[ty + i * 8][tx] = (float)ib[(size_t)(r0 + ty + i * 8) * in_stride + c0 + tx];
  __syncthreads();
#pragma unroll
  for (int i = 0; i < 4; ++i)
    ob[(size_t)(c0 + ty + i * 8) * out_stride + r0 + tx] = (OT)tile[tx][ty + i * 8];
}

// ------- combined weight prep: wqkv^T, wout^T (f32->bf16) + rope trig table -------
// grid (96, 64, 2), block (32,8).
// z=0: wqkv [2048][3072] -> qkvT [3072][2048]
// z=1, bx<64: wout [2048][2048] -> outT [2048][2048]
// z=1, bx>=64: first 256 spare blocks build tbl[p][i] = (cos, sin)(p * inv_i),
//              p in [0,2048), i in [0,32) -- exact sincosf values the old rope
//              kernel computed.
__global__ __launch_bounds__(256) void prep_weights(
    const float* __restrict__ wqkv, const float* __restrict__ wout,
    bf16_t* __restrict__ qkvT, bf16_t* __restrict__ outT,
    float2* __restrict__ tbl)
{
  const int bx = blockIdx.x, by = blockIdx.y, z = blockIdx.z;
  const int tx = threadIdx.x, ty = threadIdx.y;
  if (z == 1 && bx >= 64) {
    const int flat = (bx - 64) * 64 + by;  // 0..2047
    if (flat < 256) {
      const int idx = flat * 256 + ty * 32 + tx;  // 0..65535
      const int p = idx >> 5, i = idx & 31;
      const float inv = exp2f(-0.59161151f * (float)i);  // 500000^(-i/32)
      float sn, cs;
      sincosf((float)p * inv, &sn, &cs);
      tbl[idx] = make_float2(cs, sn);
    }
    return;
  }
  const float* in = z ? wout : wqkv;
  bf16_t* out = z ? outT : qkvT;
  const int in_stride = z ? 2048 : 3072;
  const int c0 = bx * 32, r0 = by * 32;
  __shared__ float tile[32][33];
#pragma unroll
  for (int i = 0; i < 4; ++i)
    tile[ty + i * 8][tx] = in[(size_t)(r0 + ty + i * 8) * in_stride + c0 + tx];
  __syncthreads();
#pragma unroll
  for (int i = 0; i < 4; ++i)
    out[(size_t)(c0 + ty + i * 8) * 2048 + r0 + tx] = (bf16_t)tile[tx][ty + i * 8];
}

// ---------------- GEMM: C[M,N] = A[M,K] * BT[N,K]^T ----------------
// mode 1: out = acc + resid (fp32)
// mode 2: fused qkv epilogue. Each wave's 64-col span is one head:
//   head 0-31  (q): clip->f16->rope (table) -> *qsc -> qo [B,32,S,64]
//   head 32-39 (k): clip->f16->rope (table) -> ko [B,8,S,64]
//   head 40-47 (v): clip->f16 -> outv (qkv layout, stride N; transposed later)
__global__ __launch_bounds__(256) void gemm_bt(
    const bf16_t* __restrict__ A, const bf16_t* __restrict__ BT,
    int M, int N, int K, int mode,
    const float* __restrict__ resid, void* __restrict__ outv,
    const int* __restrict__ pos, const float2* __restrict__ tbl,
    _Float16* __restrict__ qo, _Float16* __restrict__ ko)
{
  __shared__ alignas(16) bf16_t As[128 * 32];
  __shared__ alignas(16) bf16_t Bs[128 * 32];
  const int t = threadIdx.x;
  const int lane = t & 63;
  const int wave = t >> 6;
  const int m0 = blockIdx.y * 128;
  const int n0 = blockIdx.x * 128;
  const int wm = (wave >> 1) * 64;
  const int wn = (wave & 1) * 64;

  f32x4 acc[4][4] = {};

  const int i0 = t, i1 = t + 256;
  const bf16_t* Ag0 = A + (size_t)(m0 + (i0 >> 2)) * K + (i0 & 3) * 8;
  const bf16_t* Ag1 = A + (size_t)(m0 + (i1 >> 2)) * K + (i1 & 3) * 8;
  const bf16_t* Bg0 = BT + (size_t)(n0 + (i0 >> 2)) * K + (i0 & 3) * 8;
  const bf16_t* Bg1 = BT + (size_t)(n0 + (i1 >> 2)) * K + (i1 & 3) * 8;
  bf16_t* AsW0 = As + (size_t)(wave * 64) * 8;
  bf16_t* AsW1 = As + (size_t)(256 + wave * 64) * 8;
  bf16_t* BsW0 = Bs + (size_t)(wave * 64) * 8;
  bf16_t* BsW1 = Bs + (size_t)(256 + wave * 64) * 8;

  const int rsel = lane & 15;
  const int ksel = (lane >> 4) * 8;

  for (int k0 = 0; k0 < K; k0 += 32) {
    __syncthreads();
    load_lds16(Ag0 + k0, AsW0);
    load_lds16(Ag1 + k0, AsW1);
    load_lds16(Bg0 + k0, BsW0);
    load_lds16(Bg1 + k0, BsW1);
    __syncthreads();
    bf16x8 af[4], bfr[4];
#pragma unroll
    for (int i = 0; i < 4; ++i) {
      af[i]  = *(const bf16x8*)(As + (wm + i * 16 + rsel) * 32 + ksel);
      bfr[i] = *(const bf16x8*)(Bs + (wn + i * 16 + rsel) * 32 + ksel);
    }
#pragma unroll
    for (int mi = 0; mi < 4; ++mi)
#pragma unroll
      for (int ni = 0; ni < 4; ++ni)
        acc[mi][ni] = __builtin_amdgcn_mfma_f32_16x16x32_bf16(af[mi], bfr[ni], acc[mi][ni], 0, 0, 0);
  }

  const int row_l = (lane >> 4) * 4;
  const int col_l = lane & 15;
  if (mode == 1) {
#pragma unroll
    for (int mi = 0; mi < 4; ++mi) {
#pragma unroll
      for (int ni = 0; ni < 4; ++ni) {
        const size_t base = (size_t)(m0 + wm + mi * 16 + row_l) * N + (size_t)(n0 + wn + ni * 16 + col_l);
#pragma unroll
        for (int r = 0; r < 4; ++r)
          ((float*)outv)[base + (size_t)r * N] = acc[mi][ni][r] + resid[base + (size_t)r * N];
      }
    }
  } else {
    const int headg = (n0 + wn) >> 6;  // global head 0..47
    if (headg >= 40) {
      // v: clip -> f16 into qkv-layout buffer (transposed by a later kernel)
#pragma unroll
      for (int mi = 0; mi < 4; ++mi) {
#pragma unroll
        for (int ni = 0; ni < 4; ++ni) {
          const size_t base = (size_t)(m0 + wm + mi * 16 + row_l) * N + (size_t)(n0 + wn + ni * 16 + col_l);
#pragma unroll
          for (int r = 0; r < 4; ++r) {
            const float vv = fminf(8.0f, fmaxf(-8.0f, acc[mi][ni][r]));
            ((_Float16*)outv)[base + (size_t)r * N] = (_Float16)vv;
          }
        }
      }
    } else {
      const bool isq = headg < 32;
      const int bb = m0 >> 11;  // batch (rows of a block stay in one batch)
      _Float16* hb = isq ? (qo + (size_t)(bb * 32 + headg) * 2048 * 64)
                         : (ko + (size_t)(bb * 8 + (headg - 32)) * 2048 * 64);
      const float sc = isq ? 0.125f * LOG2E : 1.0f;
#pragma unroll
      for (int mi = 0; mi < 4; ++mi) {
#pragma unroll
        for (int r = 0; r < 4; ++r) {
          const int m = m0 + wm + mi * 16 + row_l + r;
          const int s = m & 2047;
          const int p = pos[m];
          const float2* tp = tbl + (size_t)p * 32;
          _Float16* drow = hb + (size_t)s * 64;
#pragma unroll
          for (int ni = 0; ni < 2; ++ni) {
            const int i = ni * 16 + col_l;  // 0..31
            const float2 cssn = tp[i];
            const float x1 = (float)(_Float16)fminf(8.0f, fmaxf(-8.0f, acc[mi][ni][r]));
            const float x2 = (float)(_Float16)fminf(8.0f, fmaxf(-8.0f, acc[mi][ni + 2][r]));
            drow[i]      = (_Float16)((x1 * cssn.x - x2 * cssn.y) * sc);
            drow[i + 32] = (_Float16)((x2 * cssn.x + x1 * cssn.y) * sc);
          }
        }
      }
    }
  }
}

// ---------------- causal GQA flash attention, KVBLK=64, defer-max ----------------
// Q [B,32,S,64] (pre-scaled), K [B,8,S,64], Vt [B,8,64,S]  (all f16)
// Out bf16 [B*S, 2048] (row = b*2048+s, col = h*64+d)
// grid (32, KVH=8, B=2), block = 512 (8 waves = 4 GQA heads x 2 16-row tiles).
// Uniform 33 slots/block via (bx, 63-bx) chunk pairing. 3 LDS buffers, depth-2
// prefetch, counted vmcnt(2), ONE s_barrier per slot (stage for J+2 issued after
// barrier J targets buf[(J-1)%3] whose readers finished pre-barrier).
// Softmax: T13 defer-max (THR=8 log2 units). Steady state uses only the IN-LANE
// max (v_max3 tree, no cross-lane shuffles) checked vs m_r+8; P=exp2(S-m_r)<=256,
// safe for f32 l / f16 P. Rare path (max grew >8): 2-shuffle full reduce +
// rescale. Row-sum l accumulated via MFMA with an all-ones B operand (ovl) --
// lands in O-row layout, so no sum tree, no l shuffles, no epilogue shuffle.
#define STAGE_TO(J, SI) do { \
    _Float16* d_ = &KV[(SI)][ksel][wv4]; \
    const _Float16* s_ = gsrc + (size_t)(J) * gstep; \
    load_lds16(s_, d_); \
    load_lds16(s_ + 32, d_ + 2048); \
  } while (0)

#define ABODY(J, BI, SI) do { \
    const int j_ = (J); \
    if (j_ == nit - 1) asm volatile("s_waitcnt vmcnt(0)" ::: "memory"); \
    else               asm volatile("s_waitcnt vmcnt(2)" ::: "memory"); \
    __builtin_amdgcn_s_barrier(); \
    __builtin_amdgcn_sched_barrier(0); \
    if (j_ + 2 < nit) STAGE_TO(j_ + 2, SI); \
    const _Float16* Kbuf = &KV[(BI)][0][0]; \
    const _Float16* Vbuf = &KV[(BI)][1][0]; \
    f32x4 st[4] = {}; \
    __builtin_amdgcn_s_setprio(1); \
    _Pragma("unroll") \
    for (int mt_ = 0; mt_ < 4; ++mt_) { \
      const f16x8v kf0_ = *(const f16x8v*)(Kbuf + krowc[mt_]); \
      const f16x8v kf1_ = *(const f16x8v*)(Kbuf + 2048 + krowc[mt_]); \
      st[mt_] = __builtin_amdgcn_mfma_f32_16x16x32_f16(kf0_, qf0, st[mt_], 0, 0, 0); \
      st[mt_] = __builtin_amdgcn_mfma_f32_16x16x32_f16(kf1_, qf1, st[mt_], 0, 0, 0); \
    } \
    __builtin_amdgcn_s_setprio(0); \
    /* V frags now: independent of softmax, in flight during max/exp */ \
    f16x4v vA_[4], vB_[4], vC_[4], vD_[4]; \
    _Pragma("unroll") \
    for (int nt_ = 0; nt_ < 4; ++nt_) { \
      const _Float16* Vr_ = Vbuf + vrow[nt_]; \
      vA_[nt_] = *(const f16x4v*)(Vr_ + vca); \
      vB_[nt_] = *(const f16x4v*)(Vr_ + vcb); \
      vC_[nt_] = *(const f16x4v*)(Vr_ + 2048 + vca); \
      vD_[nt_] = *(const f16x4v*)(Vr_ + 2048 + vcb); \
    } \
    const int k0_ = j_ * 64; \
    if (k0_ + 64 > q0) { \
      _Pragma("unroll") \
      for (int mt_ = 0; mt_ < 4; ++mt_) \
        _Pragma("unroll") \
        for (int r_ = 0; r_ < 4; ++r_) { \
          if (k0_ + mt_ * 16 + lg * 4 + r_ > myq) st[mt_][r_] = -3.0e38f; \
        } \
    } \
    /* in-lane max (clang folds fmax triples to v_max3_f32) */ \
    const float x0_ = fmaxf(fmaxf(st[0][0], st[0][1]), st[0][2]); \
    const float x1_ = fmaxf(fmaxf(st[0][3], st[1][0]), st[1][1]); \
    const float x2_ = fmaxf(fmaxf(st[1][2], st[1][3]), st[2][0]); \
    const float x3_ = fmaxf(fmaxf(st[2][1], st[2][2]), st[2][3]); \
    const float x4_ = fmaxf(fmaxf(st[3][0], st[3][1]), st[3][2]); \
    float mx_ = fmaxf(fmaxf(fmaxf(x0_, x1_), fmaxf(x2_, x3_)), fmaxf(x4_, st[3][3])); \
    if (__any(mx_ > m_r + 8.0f)) {  /* rare: full reduce + rescale */ \
      mx_ = fmaxf(mx_, __shfl_xor(mx_, 16, 64)); \
      mx_ = fmaxf(mx_, __shfl_xor(mx_, 32, 64)); \
      const float mn_ = fmaxf(m_r, mx_); \
      const float al_ = exp2f(m_r - mn_); \
      _Pragma("unroll") \
      for (int r_ = 0; r_ < 4; ++r_) { \
        const float ao_ = __shfl(al_, lg * 4 + r_, 16); \
        ov[0][r_] *= ao_; ov[1][r_] *= ao_; ov[2][r_] *= ao_; ov[3][r_] *= ao_; \
        ovl[r_] *= ao_; \
      } \
      m_r = mn_; \
    } \
    f16x4v pf_[4]; \
    _Pragma("unroll") \
    for (int mt_ = 0; mt_ < 4; ++mt_) { \
      pf_[mt_] = pack4_f16(exp2f(st[mt_][0] - m_r), exp2f(st[mt_][1] - m_r), \
                           exp2f(st[mt_][2] - m_r), exp2f(st[mt_][3] - m_r)); \
    } \
    __builtin_amdgcn_s_setprio(1); \
    _Pragma("unroll") \
    for (int nt_ = 0; nt_ < 4; ++nt_) { \
      ov[nt_] = __builtin_amdgcn_mfma_f32_16x16x16f16(pf_[0], vA_[nt_], ov[nt_], 0, 0, 0); \
      ov[nt_] = __builtin_amdgcn_mfma_f32_16x16x16f16(pf_[1], vB_[nt_], ov[nt_], 0, 0, 0); \
      ov[nt_] = __builtin_amdgcn_mfma_f32_16x16x16f16(pf_[2], vC_[nt_], ov[nt_], 0, 0, 0); \
      ov[nt_] = __builtin_amdgcn_mfma_f32_16x16x16f16(pf_[3], vD_[nt_], ov[nt_], 0, 0, 0); \
    } \
    ovl = __builtin_amdgcn_mfma_f32_16x16x16f16(pf_[0], onesv, ovl, 0, 0, 0); \
    ovl = __builtin_amdgcn_mfma_f32_16x16x16f16(pf_[1], onesv, ovl, 0, 0, 0); \
    ovl = __builtin_amdgcn_mfma_f32_16x16x16f16(pf_[2], onesv, ovl, 0, 0, 0); \
    ovl = __builtin_amdgcn_mfma_f32_16x16x16f16(pf_[3], onesv, ovl, 0, 0, 0); \
    __builtin_amdgcn_s_setprio(0); \
  } while (0)

__global__ __launch_bounds__(512, 4) void attn_kernel(
    const _Float16* __restrict__ Q, const _Float16* __restrict__ Kb,
    const _Float16* __restrict__ Vt, bf16_t* __restrict__ Out)
{
  __shared__ alignas(16) _Float16 KV[3][2][4096];  // [buf][K=0,V=1][2x 64x32 halves]

  const int kvh = blockIdx.y;
  const int b = blockIdx.z;
  const int t = threadIdx.x;
  const int lane = t & 63;
  const int wave = t >> 6;       // 0..7
  const int g = wave >> 1;       // q-head within GQA group
  const int tile = wave & 1;     // 16-row tile within the 32-row chunk
  const int h = kvh * 4 + g;
  const int ln15 = lane & 15;    // free-index lane (q for S^T / A; d for V / B)
  const int lg = lane >> 4;      // lane group (k-offset selector)

  const _Float16* Qh = Q + ((size_t)(b * 32 + h) * 2048) * 64;
  const _Float16* Kh = Kb + ((size_t)(b * 8 + kvh) * 2048) * 64;
  const _Float16* Vh = Vt + ((size_t)(b * 8 + kvh) * 64) * 2048;

  // staging: threads 0-255 stage K (64kv x 64d), 256-511 stage V^T (64d x 64kv);
  // 2x 16B loads per thread per slot (row-halves 0-31 / 32-63).
  const bool stK = (t < 256);
  const int u = t & 255;
  const int srow = u >> 2;                             // kv for K, d for V
  const int scol = ((u & 3) ^ ((srow >> 1) & 3)) * 8;  // pre-swizzled source col
  const _Float16* gsrc = stK ? (Kh + (size_t)srow * 64 + scol)
                             : (Vh + (size_t)srow * 2048 + scol);
  const int gstep = stK ? 64 * 64 : 64;                // per-slot source advance
  const int ksel = stK ? 0 : 1;
  const int wv4 = (wave & 3) * 512;                    // wave-uniform LDS sub-base

  // compute-side swizzled LDS offsets (elements)
  const int svz = (ln15 >> 1) & 3;
  const int kc = (lg ^ svz) * 8;
  const int vca = ((lg >> 1) ^ svz) * 8 + (lg & 1) * 4;
  const int vcb = (((lg >> 1) + 2) ^ svz) * 8 + (lg & 1) * 4;
  int krowc[4], vrow[4];
#pragma unroll
  for (int i = 0; i < 4; ++i) {
    krowc[i] = (i * 16 + ln15) * 32 + kc;
    vrow[i] = (i * 16 + ln15) * 32;
  }
  const f16x4v onesv = {(_Float16)1.0f, (_Float16)1.0f, (_Float16)1.0f, (_Float16)1.0f};

  for (int half = 0; half < 2; ++half) {
    const int qc = (half == 0) ? blockIdx.x : (63 - blockIdx.x);
    const int q0 = qc * 32 + tile * 16;
    const int myq = q0 + ln15;
    const int nit = (qc >> 1) + 1;   // block-uniform slot count (64 keys/slot)

    // Q B-frags: n=ln15 (q row), k = lg*8+j (+32)
    const f16x8v qf0 = *(const f16x8v*)(Qh + (size_t)(q0 + ln15) * 64 + lg * 8);
    const f16x8v qf1 = *(const f16x8v*)(Qh + (size_t)(q0 + ln15) * 64 + 32 + lg * 8);

    f32x4 ov[4] = {};     // O: rows q=lg*4+r, cols d=nt*16+ln15
    f32x4 ovl = {};       // l accumulator, same row layout (any col)
    float m_r = 0.0f;     // running max (log2 units), uniform across lg groups

    STAGE_TO(0, 0);
    if (nit > 1) STAGE_TO(1, 1);

    int it = 0;
    for (; it + 3 <= nit; it += 3) {
      ABODY(it, 0, 2);
      ABODY(it + 1, 1, 0);
      ABODY(it + 2, 2, 1);
    }
    // tail (<=2 slots; main loop exits at a multiple of 3, so buffers are 0,1;
    // tail slots never stage: j+2 >= nit always here)
    if (it < nit) { ABODY(it, 0, 2); ++it; }
    if (it < nit) { ABODY(it, 1, 0); }

    // epilogue: O rows q=lg*4+r; l lives in the same layout (no shuffles)
#pragma unroll
    for (int r = 0; r < 4; ++r) {
      const float ilo = 1.0f / ovl[r];
      const size_t obase = ((size_t)b * 2048 + (size_t)(q0 + lg * 4 + r)) * 2048 + (size_t)h * 64;
#pragma unroll
      for (int nt = 0; nt < 4; ++nt)
        Out[obase + nt * 16 + ln15] = (bf16_t)(ov[nt][r] * ilo);
    }
    // end-of-half fence: next half's prologue stages overwrite buffers 0,1
    __builtin_amdgcn_s_barrier();
    __builtin_amdgcn_sched_barrier(0);
  }
}
#undef ABODY
#undef STAGE_TO

// ---------------- launcher ----------------
extern "C" void kernel_launch(void* const* d_in, const int* in_sizes, int n_in,
                              void* d_out, int out_size, void* d_ws, size_t ws_size,
                              hipStream_t stream) {
  (void)in_sizes; (void)n_in; (void)out_size; (void)ws_size;
  const float* hid  = (const float*)d_in[0];
  const int*   pos  = (const int*)d_in[2];
  const float* ln1g = (const float*)d_in[4];
  const float* wqkv = (const float*)d_in[5];
  const float* wout = (const float*)d_in[6];
  const float* ln2g = (const float*)d_in[7];
  float* out = (float*)d_out;
  char* ws = (char*)d_ws;

  // workspace layout (bytes); peak ~100 MB
  bf16_t*   xb  = (bf16_t*)(ws + 0);          // 16.7MB x_bf16, later attn_bf16
  bf16_t*   wT  = (bf16_t*)(ws + 16777216);   // 12.6MB wqkvT
  _Float16* qkv = (_Float16*)(ws + 29360128); // 25.2MB qkv f16 (v cols only now)
  float2*   tbl = (float2*)(ws + 54525952);   // 0.5MB rope trig table
  bf16_t*   wOT = (bf16_t*)(ws + 55050240);   // 8.4MB woutT
  _Float16* qb  = (_Float16*)(ws + 79691776); // 16.8MB q (f16, pre-scaled)
  _Float16* kb  = (_Float16*)(ws + 96468992); // 4.2MB k (f16)
  _Float16* vt  = (_Float16*)(ws + 100663296);// 4.2MB v^T (f16)  end 104857600

  // 1. LN1 -> x bf16
  ln_kernel<<<4096, 256, 0, stream>>>(hid, ln1g, xb, nullptr);
  // 2. wqkv^T + wout^T + rope trig table, one launch
  prep_weights<<<dim3(96, 64, 2), dim3(32, 8), 0, stream>>>(wqkv, wout, wT, wOT, tbl);
  // 3. qkv GEMM with fused clip + rope + scatter epilogue (q->qb, k->kb, v->qkv)
  gemm_bt<<<dim3(24, 32), 256, 0, stream>>>(xb, wT, 4096, 3072, 2048, 2, nullptr, qkv,
                                            pos, tbl, qb, kb);
  // 4. v part -> vt [B,8,64,S] f16
  transpose_cast<_Float16, _Float16><<<dim3(16, 64, 2), dim3(32, 8), 0, stream>>>(
      qkv + 2560, vt, 3072, 2048, (long)2048 * 3072, (long)512 * 2048);
  // 5. attention -> xb (attn bf16 [4096][2048]; x dead)
  attn_kernel<<<dim3(32, 8, 2), 512, 0, stream>>>(qb, kb, vt, xb);
  // 6. residual2 = attn @ w_out + hid -> out[0:8388608]
  gemm_bt<<<dim3(16, 32), 256, 0, stream>>>(xb, wOT, 4096, 2048, 2048, 1, hid, out,
                                            nullptr, nullptr, nullptr, nullptr);
  // 7. LN2 -> out[8388608:16777216]
  ln_kernel<<<4096, 256, 0, stream>>>(out, ln2g, nullptr, out + 8388608);
}

// Round 6
// 374.620 us; speedup vs baseline: 1.0250x; 1.0250x over previous
//
#include <hip/hip_runtime.h>
#include <hip/hip_bf16.h>
#include <stdint.h>

typedef __bf16 bf16_t;
typedef __bf16 bf16x8 __attribute__((ext_vector_type(8)));
typedef float f32x4 __attribute__((ext_vector_type(4)));
typedef _Float16 f16x8v __attribute__((ext_vector_type(8)));
typedef _Float16 f16x4v __attribute__((ext_vector_type(4)));

#define LOG2E 1.44269504088896f

// async global->LDS, 16B per lane. LDS dest must be wave-uniform base; data
// lands at base + lane*16.
__device__ __forceinline__ void load_lds16(const void* g, void* l) {
  __builtin_amdgcn_global_load_lds(
      (__attribute__((address_space(1))) unsigned int*)(uintptr_t)(g),
      (__attribute__((address_space(3))) unsigned int*)(l),
      16, 0, 0);
}

// pack 4 floats -> f16x4v via v_cvt_pkrtz_f16_f32 pairs (builtin returns
// __fp16 vectors; bit-cast to the _Float16 vector type used by MFMA operands)
__device__ __forceinline__ f16x4v pack4_f16(float a, float b, float c, float d) {
  const __fp16 __attribute__((ext_vector_type(2))) lo = __builtin_amdgcn_cvt_pkrtz(a, b);
  const __fp16 __attribute__((ext_vector_type(2))) hi = __builtin_amdgcn_cvt_pkrtz(c, d);
  return __builtin_bit_cast(f16x4v, __builtin_shufflevector(lo, hi, 0, 1, 2, 3));
}

// ---------------- LayerNorm over rows of 2048 fp32 ----------------
__global__ __launch_bounds__(256) void ln_kernel(
    const float* __restrict__ in, const float* __restrict__ gamma,
    bf16_t* __restrict__ out_bf, float* __restrict__ out_f)
{
  const int row = blockIdx.x;
  const int t = threadIdx.x;
  const float* x = in + (size_t)row * 2048;
  float4 a = ((const float4*)x)[t];
  float4 b = ((const float4*)x)[t + 256];
  float v[8] = {a.x, a.y, a.z, a.w, b.x, b.y, b.z, b.w};
  float s = 0.f, q = 0.f;
#pragma unroll
  for (int i = 0; i < 8; ++i) { s += v[i]; q += v[i] * v[i]; }
#pragma unroll
  for (int off = 1; off < 64; off <<= 1) {
    s += __shfl_xor(s, off, 64);
    q += __shfl_xor(q, off, 64);
  }
  __shared__ float red[4][2];
  if ((t & 63) == 0) { red[t >> 6][0] = s; red[t >> 6][1] = q; }
  __syncthreads();
  s = red[0][0] + red[1][0] + red[2][0] + red[3][0];
  q = red[0][1] + red[1][1] + red[2][1] + red[3][1];
  const float mean = s * (1.0f / 2048.0f);
  const float var = q * (1.0f / 2048.0f) - mean * mean;
  const float inv = rsqrtf(var + 1e-6f);
  float4 ga = ((const float4*)gamma)[t];
  float4 gb = ((const float4*)gamma)[t + 256];
  float g[8] = {ga.x, ga.y, ga.z, ga.w, gb.x, gb.y, gb.z, gb.w};
  float y[8];
#pragma unroll
  for (int i = 0; i < 8; ++i) y[i] = (v[i] - mean) * inv * g[i];
  if (out_bf) {
    alignas(16) bf16_t tb[8];
#pragma unroll
    for (int i = 0; i < 8; ++i) tb[i] = (bf16_t)y[i];
    bf16_t* o = out_bf + (size_t)row * 2048;
    *(uint2*)(o + t * 4) = *(const uint2*)(tb);
    *(uint2*)(o + (t + 256) * 4) = *(const uint2*)(tb + 4);
  } else {
    float* o = out_f + (size_t)row * 2048;
    ((float4*)o)[t] = make_float4(y[0], y[1], y[2], y[3]);
    ((float4*)o)[t + 256] = make_float4(y[4], y[5], y[6], y[7]);
  }
}

// ------- fused pre-pass: LN1 + wqkv^T + wout^T + rope trig table, one launch -------
// grid 1D (14592 blocks, 256 thr):
//   [0,4096)          : LN1 row = bid (hid f32 -> xb bf16)
//   [4096,10240)      : wqkv [2048][3072] -> wT [3072][2048] bf16 (96x64 tiles)
//   [10240,14336)     : wout [2048][2048] -> wOT [2048][2048] bf16 (64x64 tiles)
//   [14336,14592)     : tbl[p][i] = (cos,sin)(p * 500000^(-i/32)), p<2048, i<32
__global__ __launch_bounds__(256) void fused_pre(
    const float* __restrict__ hid, const float* __restrict__ ln1g,
    bf16_t* __restrict__ xb,
    const float* __restrict__ wqkv, const float* __restrict__ wout,
    bf16_t* __restrict__ wT, bf16_t* __restrict__ wOT,
    float2* __restrict__ tbl)
{
  const int bid = blockIdx.x;
  const int t = threadIdx.x;
  if (bid < 4096) {
    const float* x = hid + (size_t)bid * 2048;
    float4 a = ((const float4*)x)[t];
    float4 b = ((const float4*)x)[t + 256];
    float v[8] = {a.x, a.y, a.z, a.w, b.x, b.y, b.z, b.w};
    float s = 0.f, q = 0.f;
#pragma unroll
    for (int i = 0; i < 8; ++i) { s += v[i]; q += v[i] * v[i]; }
#pragma unroll
    for (int off = 1; off < 64; off <<= 1) {
      s += __shfl_xor(s, off, 64);
      q += __shfl_xor(q, off, 64);
    }
    __shared__ float red[4][2];
    if ((t & 63) == 0) { red[t >> 6][0] = s; red[t >> 6][1] = q; }
    __syncthreads();
    s = red[0][0] + red[1][0] + red[2][0] + red[3][0];
    q = red[0][1] + red[1][1] + red[2][1] + red[3][1];
    const float mean = s * (1.0f / 2048.0f);
    const float var = q * (1.0f / 2048.0f) - mean * mean;
    const float inv = rsqrtf(var + 1e-6f);
    float4 ga = ((const float4*)ln1g)[t];
    float4 gb = ((const float4*)ln1g)[t + 256];
    float g[8] = {ga.x, ga.y, ga.z, ga.w, gb.x, gb.y, gb.z, gb.w};
    alignas(16) bf16_t tb[8];
#pragma unroll
    for (int i = 0; i < 8; ++i) tb[i] = (bf16_t)((v[i] - mean) * inv * g[i]);
    bf16_t* o = xb + (size_t)bid * 2048;
    *(uint2*)(o + t * 4) = *(const uint2*)(tb);
    *(uint2*)(o + (t + 256) * 4) = *(const uint2*)(tb + 4);
    return;
  }
  if (bid >= 14336) {
    const int idx = (bid - 14336) * 256 + t;  // 0..65535
    const int p = idx >> 5, i = idx & 31;
    const float inv = exp2f(-0.59161151f * (float)i);  // 500000^(-i/32)
    float sn, cs;
    sincosf((float)p * inv, &sn, &cs);
    tbl[idx] = make_float2(cs, sn);
    return;
  }
  // weight transposes
  const bool isQ = bid < 10240;
  const int i6 = isQ ? (bid - 4096) : (bid - 10240);
  const int bx = isQ ? (i6 % 96) : (i6 & 63);
  const int by = isQ ? (i6 / 96) : (i6 >> 6);
  const float* in = isQ ? wqkv : wout;
  bf16_t* out = isQ ? wT : wOT;
  const int in_stride = isQ ? 3072 : 2048;
  const int c0 = bx * 32, r0 = by * 32;
  const int tx = t & 31, ty = t >> 5;
  __shared__ float tile[32][33];
#pragma unroll
  for (int i = 0; i < 4; ++i)
    tile[ty + i * 8][tx] = in[(size_t)(r0 + ty + i * 8) * in_stride + c0 + tx];
  __syncthreads();
#pragma unroll
  for (int i = 0; i < 4; ++i)
    out[(size_t)(c0 + ty + i * 8) * 2048 + r0 + tx] = (bf16_t)tile[tx][ty + i * 8];
}

// ------- fused rope (table) + V-transpose, one launch -------
// grid 1D (6144 blocks, 256 thr):
//   [0,4096)    : rope row bs = bid. qkv f16 [4096][3072] (clipped) ->
//                 qo [B,32,S,64] (pre-scaled by 0.125*log2e), ko [B,8,S,64]
//   [4096,6144) : v cols -> vt [B,8,64,S]: 2048 32x32 tiles (16 x 64 x 2)
__global__ __launch_bounds__(256) void rope_v(
    const _Float16* __restrict__ qkv, const int* __restrict__ pos_ids,
    const float2* __restrict__ tbl,
    _Float16* __restrict__ qo, _Float16* __restrict__ ko,
    _Float16* __restrict__ vt)
{
  const int bid = blockIdx.x;
  const int t = threadIdx.x;
  __shared__ float tile[32][33];
  if (bid < 4096) {
    const int b = bid >> 11, s = bid & 2047;
    const float2* tp = tbl + (size_t)pos_ids[bid] * 32;
    const _Float16* row = qkv + (size_t)bid * 3072;
    const float qsc = 0.125f * LOG2E;
#pragma unroll
    for (int pp = 0; pp < 4; ++pp) {
      const int p = t + pp * 256;
      const int hh = p >> 5, i = p & 31;
      const float2 cssn = tp[i];
      const float x1 = (float)row[hh * 64 + i];
      const float x2 = (float)row[hh * 64 + 32 + i];
      _Float16* d = qo + (((size_t)b * 32 + hh) * 2048 + s) * 64 + i;
      d[0] = (_Float16)((x1 * cssn.x - x2 * cssn.y) * qsc);
      d[32] = (_Float16)((x2 * cssn.x + x1 * cssn.y) * qsc);
    }
    {
      const int hh = t >> 5, i = t & 31;
      const float2 cssn = tp[i];
      const float x1 = (float)row[2048 + hh * 64 + i];
      const float x2 = (float)row[2048 + hh * 64 + 32 + i];
      _Float16* d = ko + (((size_t)b * 8 + hh) * 2048 + s) * 64 + i;
      d[0] = (_Float16)(x1 * cssn.x - x2 * cssn.y);
      d[32] = (_Float16)(x2 * cssn.x + x1 * cssn.y);
    }
    return;
  }
  const int idx = bid - 4096;          // 0..2047
  const int bz = idx >> 10;            // batch
  const int rem = idx & 1023;
  const int bx = rem & 15, by = rem >> 4;
  const _Float16* ib = qkv + 2560 + (size_t)bz * 2048 * 3072;
  _Float16* ob = vt + (size_t)bz * 512 * 2048;
  const int c0 = bx * 32, r0 = by * 32;
  const int tx = t & 31, ty = t >> 5;
#pragma unroll
  for (int i = 0; i < 4; ++i)
    tile[ty + i * 8][tx] = (float)ib[(size_t)(r0 + ty + i * 8) * 3072 + c0 + tx];
  __syncthreads();
#pragma unroll
  for (int i = 0; i < 4; ++i)
    ob[(size_t)(c0 + ty + i * 8) * 2048 + r0 + tx] = (_Float16)tile[tx][ty + i * 8];
}

// ---------------- GEMM: C[M,N] = A[M,K] * BT[N,K]^T ----------------
// mode 0: clip(+-8) -> out f16    mode 1: out = acc + resid (fp32)
__global__ __launch_bounds__(256) void gemm_bt(
    const bf16_t* __restrict__ A, const bf16_t* __restrict__ BT,
    int M, int N, int K, int mode,
    const float* __restrict__ resid, void* __restrict__ outv)
{
  __shared__ alignas(16) bf16_t As[128 * 32];
  __shared__ alignas(16) bf16_t Bs[128 * 32];
  const int t = threadIdx.x;
  const int lane = t & 63;
  const int wave = t >> 6;
  const int m0 = blockIdx.y * 128;
  const int n0 = blockIdx.x * 128;
  const int wm = (wave >> 1) * 64;
  const int wn = (wave & 1) * 64;

  f32x4 acc[4][4] = {};

  const int i0 = t, i1 = t + 256;
  const bf16_t* Ag0 = A + (size_t)(m0 + (i0 >> 2)) * K + (i0 & 3) * 8;
  const bf16_t* Ag1 = A + (size_t)(m0 + (i1 >> 2)) * K + (i1 & 3) * 8;
  const bf16_t* Bg0 = BT + (size_t)(n0 + (i0 >> 2)) * K + (i0 & 3) * 8;
  const bf16_t* Bg1 = BT + (size_t)(n0 + (i1 >> 2)) * K + (i1 & 3) * 8;
  bf16_t* AsW0 = As + (size_t)(wave * 64) * 8;
  bf16_t* AsW1 = As + (size_t)(256 + wave * 64) * 8;
  bf16_t* BsW0 = Bs + (size_t)(wave * 64) * 8;
  bf16_t* BsW1 = Bs + (size_t)(256 + wave * 64) * 8;

  const int rsel = lane & 15;
  const int ksel = (lane >> 4) * 8;

  for (int k0 = 0; k0 < K; k0 += 32) {
    __syncthreads();
    load_lds16(Ag0 + k0, AsW0);
    load_lds16(Ag1 + k0, AsW1);
    load_lds16(Bg0 + k0, BsW0);
    load_lds16(Bg1 + k0, BsW1);
    __syncthreads();
    bf16x8 af[4], bfr[4];
#pragma unroll
    for (int i = 0; i < 4; ++i) {
      af[i]  = *(const bf16x8*)(As + (wm + i * 16 + rsel) * 32 + ksel);
      bfr[i] = *(const bf16x8*)(Bs + (wn + i * 16 + rsel) * 32 + ksel);
    }
#pragma unroll
    for (int mi = 0; mi < 4; ++mi)
#pragma unroll
      for (int ni = 0; ni < 4; ++ni)
        acc[mi][ni] = __builtin_amdgcn_mfma_f32_16x16x32_bf16(af[mi], bfr[ni], acc[mi][ni], 0, 0, 0);
  }

  const int row_l = (lane >> 4) * 4;
  const int col_l = lane & 15;
#pragma unroll
  for (int mi = 0; mi < 4; ++mi) {
#pragma unroll
    for (int ni = 0; ni < 4; ++ni) {
      const size_t base = (size_t)(m0 + wm + mi * 16 + row_l) * N + (size_t)(n0 + wn + ni * 16 + col_l);
#pragma unroll
      for (int r = 0; r < 4; ++r) {
        float vv = acc[mi][ni][r];
        if (mode == 0) {
          vv = fminf(8.0f, fmaxf(-8.0f, vv));
          ((_Float16*)outv)[base + (size_t)r * N] = (_Float16)vv;
        } else {
          ((float*)outv)[base + (size_t)r * N] = vv + resid[base + (size_t)r * N];
        }
      }
    }
  }
}

// ---------------- causal GQA flash attention, KVBLK=64, defer-max ----------------
// Q [B,32,S,64] (pre-scaled), K [B,8,S,64], Vt [B,8,64,S]  (all f16)
// Out bf16 [B*S, 2048] (row = b*2048+s, col = h*64+d)
// grid (32, KVH=8, B=2), block = 512 (8 waves = 4 GQA heads x 2 16-row tiles).
// Uniform 33 slots/block via (bx, 63-bx) chunk pairing. 3 LDS buffers, depth-2
// prefetch, counted vmcnt(2), ONE s_barrier per slot (stage for J+2 issued after
// barrier J targets buf[(J-1)%3] whose readers finished pre-barrier).
// Softmax: T13 defer-max (THR=8 log2 units). Steady state uses only the IN-LANE
// max (v_max3 tree, no cross-lane shuffles) checked vs m_r+8; P=exp2(S-m_r)<=256,
// safe for f32 l / f16 P. Rare path (max grew >8): 2-shuffle full reduce +
// rescale. Row-sum l accumulated via MFMA with an all-ones B operand (ovl) --
// lands in O-row layout, so no sum tree, no l shuffles, no epilogue shuffle.
#define STAGE_TO(J, SI) do { \
    _Float16* d_ = &KV[(SI)][ksel][wv4]; \
    const _Float16* s_ = gsrc + (size_t)(J) * gstep; \
    load_lds16(s_, d_); \
    load_lds16(s_ + 32, d_ + 2048); \
  } while (0)

#define ABODY(J, BI, SI) do { \
    const int j_ = (J); \
    if (j_ == nit - 1) asm volatile("s_waitcnt vmcnt(0)" ::: "memory"); \
    else               asm volatile("s_waitcnt vmcnt(2)" ::: "memory"); \
    __builtin_amdgcn_s_barrier(); \
    __builtin_amdgcn_sched_barrier(0); \
    if (j_ + 2 < nit) STAGE_TO(j_ + 2, SI); \
    const _Float16* Kbuf = &KV[(BI)][0][0]; \
    const _Float16* Vbuf = &KV[(BI)][1][0]; \
    f32x4 st[4] = {}; \
    __builtin_amdgcn_s_setprio(1); \
    _Pragma("unroll") \
    for (int mt_ = 0; mt_ < 4; ++mt_) { \
      const f16x8v kf0_ = *(const f16x8v*)(Kbuf + krowc[mt_]); \
      const f16x8v kf1_ = *(const f16x8v*)(Kbuf + 2048 + krowc[mt_]); \
      st[mt_] = __builtin_amdgcn_mfma_f32_16x16x32_f16(kf0_, qf0, st[mt_], 0, 0, 0); \
      st[mt_] = __builtin_amdgcn_mfma_f32_16x16x32_f16(kf1_, qf1, st[mt_], 0, 0, 0); \
    } \
    __builtin_amdgcn_s_setprio(0); \
    /* V frags now: independent of softmax, in flight during max/exp */ \
    f16x4v vA_[4], vB_[4], vC_[4], vD_[4]; \
    _Pragma("unroll") \
    for (int nt_ = 0; nt_ < 4; ++nt_) { \
      const _Float16* Vr_ = Vbuf + vrow[nt_]; \
      vA_[nt_] = *(const f16x4v*)(Vr_ + vca); \
      vB_[nt_] = *(const f16x4v*)(Vr_ + vcb); \
      vC_[nt_] = *(const f16x4v*)(Vr_ + 2048 + vca); \
      vD_[nt_] = *(const f16x4v*)(Vr_ + 2048 + vcb); \
    } \
    const int k0_ = j_ * 64; \
    if (k0_ + 64 > q0) { \
      _Pragma("unroll") \
      for (int mt_ = 0; mt_ < 4; ++mt_) \
        _Pragma("unroll") \
        for (int r_ = 0; r_ < 4; ++r_) { \
          if (k0_ + mt_ * 16 + lg * 4 + r_ > myq) st[mt_][r_] = -3.0e38f; \
        } \
    } \
    /* in-lane max (clang folds fmax triples to v_max3_f32) */ \
    const float x0_ = fmaxf(fmaxf(st[0][0], st[0][1]), st[0][2]); \
    const float x1_ = fmaxf(fmaxf(st[0][3], st[1][0]), st[1][1]); \
    const float x2_ = fmaxf(fmaxf(st[1][2], st[1][3]), st[2][0]); \
    const float x3_ = fmaxf(fmaxf(st[2][1], st[2][2]), st[2][3]); \
    const float x4_ = fmaxf(fmaxf(st[3][0], st[3][1]), st[3][2]); \
    float mx_ = fmaxf(fmaxf(fmaxf(x0_, x1_), fmaxf(x2_, x3_)), fmaxf(x4_, st[3][3])); \
    if (__any(mx_ > m_r + 8.0f)) {  /* rare: full reduce + rescale */ \
      mx_ = fmaxf(mx_, __shfl_xor(mx_, 16, 64)); \
      mx_ = fmaxf(mx_, __shfl_xor(mx_, 32, 64)); \
      const float mn_ = fmaxf(m_r, mx_); \
      const float al_ = exp2f(m_r - mn_); \
      _Pragma("unroll") \
      for (int r_ = 0; r_ < 4; ++r_) { \
        const float ao_ = __shfl(al_, lg * 4 + r_, 16); \
        ov[0][r_] *= ao_; ov[1][r_] *= ao_; ov[2][r_] *= ao_; ov[3][r_] *= ao_; \
        ovl[r_] *= ao_; \
      } \
      m_r = mn_; \
    } \
    f16x4v pf_[4]; \
    _Pragma("unroll") \
    for (int mt_ = 0; mt_ < 4; ++mt_) { \
      pf_[mt_] = pack4_f16(exp2f(st[mt_][0] - m_r), exp2f(st[mt_][1] - m_r), \
                           exp2f(st[mt_][2] - m_r), exp2f(st[mt_][3] - m_r)); \
    } \
    __builtin_amdgcn_s_setprio(1); \
    _Pragma("unroll") \
    for (int nt_ = 0; nt_ < 4; ++nt_) { \
      ov[nt_] = __builtin_amdgcn_mfma_f32_16x16x16f16(pf_[0], vA_[nt_], ov[nt_], 0, 0, 0); \
      ov[nt_] = __builtin_amdgcn_mfma_f32_16x16x16f16(pf_[1], vB_[nt_], ov[nt_], 0, 0, 0); \
      ov[nt_] = __builtin_amdgcn_mfma_f32_16x16x16f16(pf_[2], vC_[nt_], ov[nt_], 0, 0, 0); \
      ov[nt_] = __builtin_amdgcn_mfma_f32_16x16x16f16(pf_[3], vD_[nt_], ov[nt_], 0, 0, 0); \
    } \
    ovl = __builtin_amdgcn_mfma_f32_16x16x16f16(pf_[0], onesv, ovl, 0, 0, 0); \
    ovl = __builtin_amdgcn_mfma_f32_16x16x16f16(pf_[1], onesv, ovl, 0, 0, 0); \
    ovl = __builtin_amdgcn_mfma_f32_16x16x16f16(pf_[2], onesv, ovl, 0, 0, 0); \
    ovl = __builtin_amdgcn_mfma_f32_16x16x16f16(pf_[3], onesv, ovl, 0, 0, 0); \
    __builtin_amdgcn_s_setprio(0); \
  } while (0)

__global__ __launch_bounds__(512, 4) void attn_kernel(
    const _Float16* __restrict__ Q, const _Float16* __restrict__ Kb,
    const _Float16* __restrict__ Vt, bf16_t* __restrict__ Out)
{
  __shared__ alignas(16) _Float16 KV[3][2][4096];  // [buf][K=0,V=1][2x 64x32 halves]

  const int kvh = blockIdx.y;
  const int b = blockIdx.z;
  const int t = threadIdx.x;
  const int lane = t & 63;
  const int wave = t >> 6;       // 0..7
  const int g = wave >> 1;       // q-head within GQA group
  const int tile = wave & 1;     // 16-row tile within the 32-row chunk
  const int h = kvh * 4 + g;
  const int ln15 = lane & 15;    // free-index lane (q for S^T / A; d for V / B)
  const int lg = lane >> 4;      // lane group (k-offset selector)

  const _Float16* Qh = Q + ((size_t)(b * 32 + h) * 2048) * 64;
  const _Float16* Kh = Kb + ((size_t)(b * 8 + kvh) * 2048) * 64;
  const _Float16* Vh = Vt + ((size_t)(b * 8 + kvh) * 64) * 2048;

  // staging: threads 0-255 stage K (64kv x 64d), 256-511 stage V^T (64d x 64kv);
  // 2x 16B loads per thread per slot (row-halves 0-31 / 32-63).
  const bool stK = (t < 256);
  const int u = t & 255;
  const int srow = u >> 2;                             // kv for K, d for V
  const int scol = ((u & 3) ^ ((srow >> 1) & 3)) * 8;  // pre-swizzled source col
  const _Float16* gsrc = stK ? (Kh + (size_t)srow * 64 + scol)
                             : (Vh + (size_t)srow * 2048 + scol);
  const int gstep = stK ? 64 * 64 : 64;                // per-slot source advance
  const int ksel = stK ? 0 : 1;
  const int wv4 = (wave & 3) * 512;                    // wave-uniform LDS sub-base

  // compute-side swizzled LDS offsets (elements)
  const int svz = (ln15 >> 1) & 3;
  const int kc = (lg ^ svz) * 8;
  const int vca = ((lg >> 1) ^ svz) * 8 + (lg & 1) * 4;
  const int vcb = (((lg >> 1) + 2) ^ svz) * 8 + (lg & 1) * 4;
  int krowc[4], vrow[4];
#pragma unroll
  for (int i = 0; i < 4; ++i) {
    krowc[i] = (i * 16 + ln15) * 32 + kc;
    vrow[i] = (i * 16 + ln15) * 32;
  }
  const f16x4v onesv = {(_Float16)1.0f, (_Float16)1.0f, (_Float16)1.0f, (_Float16)1.0f};

  for (int half = 0; half < 2; ++half) {
    const int qc = (half == 0) ? blockIdx.x : (63 - blockIdx.x);
    const int q0 = qc * 32 + tile * 16;
    const int myq = q0 + ln15;
    const int nit = (qc >> 1) + 1;   // block-uniform slot count (64 keys/slot)

    // Q B-frags: n=ln15 (q row), k = lg*8+j (+32)
    const f16x8v qf0 = *(const f16x8v*)(Qh + (size_t)(q0 + ln15) * 64 + lg * 8);
    const f16x8v qf1 = *(const f16x8v*)(Qh + (size_t)(q0 + ln15) * 64 + 32 + lg * 8);

    f32x4 ov[4] = {};     // O: rows q=lg*4+r, cols d=nt*16+ln15
    f32x4 ovl = {};       // l accumulator, same row layout (any col)
    float m_r = 0.0f;     // running max (log2 units), uniform across lg groups

    STAGE_TO(0, 0);
    if (nit > 1) STAGE_TO(1, 1);

    int it = 0;
    for (; it + 3 <= nit; it += 3) {
      ABODY(it, 0, 2);
      ABODY(it + 1, 1, 0);
      ABODY(it + 2, 2, 1);
    }
    // tail (<=2 slots; main loop exits at a multiple of 3, so buffers are 0,1;
    // tail slots never stage: j+2 >= nit always here)
    if (it < nit) { ABODY(it, 0, 2); ++it; }
    if (it < nit) { ABODY(it, 1, 0); }

    // epilogue: O rows q=lg*4+r; l lives in the same layout (no shuffles)
#pragma unroll
    for (int r = 0; r < 4; ++r) {
      const float ilo = 1.0f / ovl[r];
      const size_t obase = ((size_t)b * 2048 + (size_t)(q0 + lg * 4 + r)) * 2048 + (size_t)h * 64;
#pragma unroll
      for (int nt = 0; nt < 4; ++nt)
        Out[obase + nt * 16 + ln15] = (bf16_t)(ov[nt][r] * ilo);
    }
    // end-of-half fence: next half's prologue stages overwrite buffers 0,1
    __builtin_amdgcn_s_barrier();
    __builtin_amdgcn_sched_barrier(0);
  }
}
#undef ABODY
#undef STAGE_TO

// ---------------- launcher ----------------
extern "C" void kernel_launch(void* const* d_in, const int* in_sizes, int n_in,
                              void* d_out, int out_size, void* d_ws, size_t ws_size,
                              hipStream_t stream) {
  (void)in_sizes; (void)n_in; (void)out_size; (void)ws_size;
  const float* hid  = (const float*)d_in[0];
  const int*   pos  = (const int*)d_in[2];
  const float* ln1g = (const float*)d_in[4];
  const float* wqkv = (const float*)d_in[5];
  const float* wout = (const float*)d_in[6];
  const float* ln2g = (const float*)d_in[7];
  float* out = (float*)d_out;
  char* ws = (char*)d_ws;

  // workspace layout (bytes); peak ~100 MB
  bf16_t*   xb  = (bf16_t*)(ws + 0);          // 16.7MB x_bf16, later attn_bf16
  bf16_t*   wT  = (bf16_t*)(ws + 16777216);   // 12.6MB wqkvT
  _Float16* qkv = (_Float16*)(ws + 29360128); // 25.2MB qkv f16 (clipped)
  float2*   tbl = (float2*)(ws + 54525952);   // 0.5MB rope trig table
  bf16_t*   wOT = (bf16_t*)(ws + 55050240);   // 8.4MB woutT
  _Float16* qb  = (_Float16*)(ws + 79691776); // 16.8MB q (f16, pre-scaled)
  _Float16* kb  = (_Float16*)(ws + 96468992); // 4.2MB k (f16)
  _Float16* vt  = (_Float16*)(ws + 100663296);// 4.2MB v^T (f16)  end 104857600

  // 1. LN1 + wqkv^T + wout^T + trig table (one launch, independent works)
  fused_pre<<<14592, 256, 0, stream>>>(hid, ln1g, xb, wqkv, wout, wT, wOT, tbl);
  // 2. qkv = clip(x @ w_qkv) -> f16
  gemm_bt<<<dim3(24, 32), 256, 0, stream>>>(xb, wT, 4096, 3072, 2048, 0, nullptr, qkv);
  // 3. RoPE (table) q->qb, k->kb + v -> vt [B,8,64,S] (one launch)
  rope_v<<<6144, 256, 0, stream>>>(qkv, pos, tbl, qb, kb, vt);
  // 4. attention -> xb (attn bf16 [4096][2048]; x dead)
  attn_kernel<<<dim3(32, 8, 2), 512, 0, stream>>>(qb, kb, vt, xb);
  // 5. residual2 = attn @ w_out + hid -> out[0:8388608]
  gemm_bt<<<dim3(16, 32), 256, 0, stream>>>(xb, wOT, 4096, 2048, 2048, 1, hid, out);
  // 6. LN2 -> out[8388608:16777216]
  ln_kernel<<<4096, 256, 0, stream>>>(out, ln2g, nullptr, out + 8388608);
}

// Round 7
// 358.557 us; speedup vs baseline: 1.0710x; 1.0448x over previous
//
#include <hip/hip_runtime.h>
#include <hip/hip_bf16.h>
#include <stdint.h>

typedef __bf16 bf16_t;
typedef __bf16 bf16x8 __attribute__((ext_vector_type(8)));
typedef float f32x4 __attribute__((ext_vector_type(4)));
typedef _Float16 f16x8v __attribute__((ext_vector_type(8)));
typedef _Float16 f16x4v __attribute__((ext_vector_type(4)));

#define LOG2E 1.44269504088896f

// async global->LDS, 16B per lane. LDS dest must be wave-uniform base; data
// lands at base + lane*16.
__device__ __forceinline__ void load_lds16(const void* g, void* l) {
  __builtin_amdgcn_global_load_lds(
      (__attribute__((address_space(1))) unsigned int*)(uintptr_t)(g),
      (__attribute__((address_space(3))) unsigned int*)(l),
      16, 0, 0);
}

// pack 4 floats -> f16x4v via v_cvt_pkrtz_f16_f32 pairs (builtin returns
// __fp16 vectors; bit-cast to the _Float16 vector type used by MFMA operands)
__device__ __forceinline__ f16x4v pack4_f16(float a, float b, float c, float d) {
  const __fp16 __attribute__((ext_vector_type(2))) lo = __builtin_amdgcn_cvt_pkrtz(a, b);
  const __fp16 __attribute__((ext_vector_type(2))) hi = __builtin_amdgcn_cvt_pkrtz(c, d);
  return __builtin_bit_cast(f16x4v, __builtin_shufflevector(lo, hi, 0, 1, 2, 3));
}

// ---------------- LayerNorm over rows of 2048 fp32 ----------------
__global__ __launch_bounds__(256) void ln_kernel(
    const float* __restrict__ in, const float* __restrict__ gamma,
    bf16_t* __restrict__ out_bf, float* __restrict__ out_f)
{
  const int row = blockIdx.x;
  const int t = threadIdx.x;
  const float* x = in + (size_t)row * 2048;
  float4 a = ((const float4*)x)[t];
  float4 b = ((const float4*)x)[t + 256];
  float v[8] = {a.x, a.y, a.z, a.w, b.x, b.y, b.z, b.w};
  float s = 0.f, q = 0.f;
#pragma unroll
  for (int i = 0; i < 8; ++i) { s += v[i]; q += v[i] * v[i]; }
#pragma unroll
  for (int off = 1; off < 64; off <<= 1) {
    s += __shfl_xor(s, off, 64);
    q += __shfl_xor(q, off, 64);
  }
  __shared__ float red[4][2];
  if ((t & 63) == 0) { red[t >> 6][0] = s; red[t >> 6][1] = q; }
  __syncthreads();
  s = red[0][0] + red[1][0] + red[2][0] + red[3][0];
  q = red[0][1] + red[1][1] + red[2][1] + red[3][1];
  const float mean = s * (1.0f / 2048.0f);
  const float var = q * (1.0f / 2048.0f) - mean * mean;
  const float inv = rsqrtf(var + 1e-6f);
  float4 ga = ((const float4*)gamma)[t];
  float4 gb = ((const float4*)gamma)[t + 256];
  float g[8] = {ga.x, ga.y, ga.z, ga.w, gb.x, gb.y, gb.z, gb.w};
  float y[8];
#pragma unroll
  for (int i = 0; i < 8; ++i) y[i] = (v[i] - mean) * inv * g[i];
  if (out_bf) {
    alignas(16) bf16_t tb[8];
#pragma unroll
    for (int i = 0; i < 8; ++i) tb[i] = (bf16_t)y[i];
    bf16_t* o = out_bf + (size_t)row * 2048;
    *(uint2*)(o + t * 4) = *(const uint2*)(tb);
    *(uint2*)(o + (t + 256) * 4) = *(const uint2*)(tb + 4);
  } else {
    float* o = out_f + (size_t)row * 2048;
    ((float4*)o)[t] = make_float4(y[0], y[1], y[2], y[3]);
    ((float4*)o)[t + 256] = make_float4(y[4], y[5], y[6], y[7]);
  }
}

// ------- fused pre-pass: LN1 + wqkv^T + wout^T + rope trig table, one launch -------
// grid 1D (14592 blocks, 256 thr):
//   [0,4096)          : LN1 row = bid (hid f32 -> xb bf16)
//   [4096,10240)      : wqkv [2048][3072] -> wT [3072][2048] bf16 (96x64 tiles)
//   [10240,14336)     : wout [2048][2048] -> wOT [2048][2048] bf16 (64x64 tiles)
//   [14336,14592)     : tbl[p][i] = (cos,sin)(p * 500000^(-i/32)), p<2048, i<32
// Transposes: float4 16B loads; 4x bf16 packed 8B stores; tile[32][33] reads
// with <=2-way bank aliasing (free).
__global__ __launch_bounds__(256) void fused_pre(
    const float* __restrict__ hid, const float* __restrict__ ln1g,
    bf16_t* __restrict__ xb,
    const float* __restrict__ wqkv, const float* __restrict__ wout,
    bf16_t* __restrict__ wT, bf16_t* __restrict__ wOT,
    float2* __restrict__ tbl)
{
  const int bid = blockIdx.x;
  const int t = threadIdx.x;
  if (bid < 4096) {
    const float* x = hid + (size_t)bid * 2048;
    float4 a = ((const float4*)x)[t];
    float4 b = ((const float4*)x)[t + 256];
    float v[8] = {a.x, a.y, a.z, a.w, b.x, b.y, b.z, b.w};
    float s = 0.f, q = 0.f;
#pragma unroll
    for (int i = 0; i < 8; ++i) { s += v[i]; q += v[i] * v[i]; }
#pragma unroll
    for (int off = 1; off < 64; off <<= 1) {
      s += __shfl_xor(s, off, 64);
      q += __shfl_xor(q, off, 64);
    }
    __shared__ float red[4][2];
    if ((t & 63) == 0) { red[t >> 6][0] = s; red[t >> 6][1] = q; }
    __syncthreads();
    s = red[0][0] + red[1][0] + red[2][0] + red[3][0];
    q = red[0][1] + red[1][1] + red[2][1] + red[3][1];
    const float mean = s * (1.0f / 2048.0f);
    const float var = q * (1.0f / 2048.0f) - mean * mean;
    const float inv = rsqrtf(var + 1e-6f);
    float4 ga = ((const float4*)ln1g)[t];
    float4 gb = ((const float4*)ln1g)[t + 256];
    float g[8] = {ga.x, ga.y, ga.z, ga.w, gb.x, gb.y, gb.z, gb.w};
    alignas(16) bf16_t tb[8];
#pragma unroll
    for (int i = 0; i < 8; ++i) tb[i] = (bf16_t)((v[i] - mean) * inv * g[i]);
    bf16_t* o = xb + (size_t)bid * 2048;
    *(uint2*)(o + t * 4) = *(const uint2*)(tb);
    *(uint2*)(o + (t + 256) * 4) = *(const uint2*)(tb + 4);
    return;
  }
  if (bid >= 14336) {
    const int idx = (bid - 14336) * 256 + t;  // 0..65535
    const int p = idx >> 5, i = idx & 31;
    const float inv = exp2f(-0.59161151f * (float)i);  // 500000^(-i/32)
    float sn, cs;
    sincosf((float)p * inv, &sn, &cs);
    tbl[idx] = make_float2(cs, sn);
    return;
  }
  // weight transposes
  const bool isQ = bid < 10240;
  const int i6 = isQ ? (bid - 4096) : (bid - 10240);
  const int bx = isQ ? (i6 % 96) : (i6 & 63);
  const int by = isQ ? (i6 / 96) : (i6 >> 6);
  const float* in = isQ ? wqkv : wout;
  bf16_t* out = isQ ? wT : wOT;
  const int in_stride = isQ ? 3072 : 2048;
  const int c0 = bx * 32, r0 = by * 32;
  __shared__ float tile[32][33];
  const int r = t >> 3, c4 = (t & 7) * 4;
  const float4 v4 = *(const float4*)(in + (size_t)(r0 + r) * in_stride + c0 + c4);
  tile[r][c4] = v4.x; tile[r][c4 + 1] = v4.y;
  tile[r][c4 + 2] = v4.z; tile[r][c4 + 3] = v4.w;
  __syncthreads();
  const int cc = t >> 3, rr4 = (t & 7) * 4;
  alignas(8) bf16_t obuf[4];
#pragma unroll
  for (int j = 0; j < 4; ++j) obuf[j] = (bf16_t)tile[rr4 + j][cc];
  *(uint2*)(out + (size_t)(c0 + cc) * 2048 + r0 + rr4) = *(const uint2*)obuf;
}

// ------- kv prep: k-rope (table, 16B I/O) + V-transpose (8B stores), one launch -------
// grid 1D (2560 blocks, 256 thr):
//   [0,512)     : k-rope, 8 (b,s) rows per block. qkv k-section -> ko [B,8,S,64]
//   [512,2560)  : v cols -> vt [B,8,64,S]: 32x32 tiles (2 x 64 x 16)
__global__ __launch_bounds__(256) void kv_prep(
    const _Float16* __restrict__ qkv, const int* __restrict__ pos_ids,
    const float2* __restrict__ tbl,
    _Float16* __restrict__ ko, _Float16* __restrict__ vt)
{
  const int bid = blockIdx.x;
  const int t = threadIdx.x;
  if (bid < 512) {
    const int lr = t >> 5, u = t & 31;
    const int bs = bid * 8 + lr;
    const int b = bs >> 11, s = bs & 2047;
    const int hh = u >> 2, i8 = (u & 3) * 8;
    const _Float16* row = qkv + (size_t)bs * 3072 + 2048 + hh * 64;
    const float2* tp = tbl + (size_t)pos_ids[bs] * 32 + i8;
    const f16x8v x1v = *(const f16x8v*)(row + i8);
    const f16x8v x2v = *(const f16x8v*)(row + 32 + i8);
    f16x8v y1, y2;
#pragma unroll
    for (int j = 0; j < 8; ++j) {
      const float2 cs = tp[j];
      const float x1 = (float)x1v[j], x2 = (float)x2v[j];
      y1[j] = (_Float16)(x1 * cs.x - x2 * cs.y);
      y2[j] = (_Float16)(x2 * cs.x + x1 * cs.y);
    }
    _Float16* d = ko + (((size_t)b * 8 + hh) * 2048 + s) * 64 + i8;
    *(f16x8v*)(d) = y1;
    *(f16x8v*)(d + 32) = y2;
    return;
  }
  const int idx = bid - 512;           // 0..2047
  const int bz = idx >> 10;            // batch
  const int rem = idx & 1023;
  const int bx = rem & 15, by = rem >> 4;
  const _Float16* ib = qkv + (size_t)bz * 2048 * 3072 + 2560;
  _Float16* ob = vt + (size_t)bz * 512 * 2048;
  const int c0 = bx * 32, r0 = by * 32;  // c = v-dim (col in qkv), r = s
  __shared__ float tile[32][33];
  const int r = t >> 3, c4 = (t & 7) * 4;
  const f16x4v v4 = *(const f16x4v*)(ib + (size_t)(r0 + r) * 3072 + c0 + c4);
#pragma unroll
  for (int j = 0; j < 4; ++j) tile[r][c4 + j] = (float)v4[j];
  __syncthreads();
  const int cc = t >> 3, rr4 = (t & 7) * 4;
  alignas(8) _Float16 obuf[4];
#pragma unroll
  for (int j = 0; j < 4; ++j) obuf[j] = (_Float16)tile[rr4 + j][cc];
  *(uint2*)(ob + (size_t)(c0 + cc) * 2048 + r0 + rr4) = *(const uint2*)obuf;
}

// ---------------- GEMM: C[M,N] = A[M,K] * BT[N,K]^T ----------------
// mode 0: clip(+-8) -> out f16    mode 1: out = acc + resid (fp32)
__global__ __launch_bounds__(256) void gemm_bt(
    const bf16_t* __restrict__ A, const bf16_t* __restrict__ BT,
    int M, int N, int K, int mode,
    const float* __restrict__ resid, void* __restrict__ outv)
{
  __shared__ alignas(16) bf16_t As[128 * 32];
  __shared__ alignas(16) bf16_t Bs[128 * 32];
  const int t = threadIdx.x;
  const int lane = t & 63;
  const int wave = t >> 6;
  const int m0 = blockIdx.y * 128;
  const int n0 = blockIdx.x * 128;
  const int wm = (wave >> 1) * 64;
  const int wn = (wave & 1) * 64;

  f32x4 acc[4][4] = {};

  const int i0 = t, i1 = t + 256;
  const bf16_t* Ag0 = A + (size_t)(m0 + (i0 >> 2)) * K + (i0 & 3) * 8;
  const bf16_t* Ag1 = A + (size_t)(m0 + (i1 >> 2)) * K + (i1 & 3) * 8;
  const bf16_t* Bg0 = BT + (size_t)(n0 + (i0 >> 2)) * K + (i0 & 3) * 8;
  const bf16_t* Bg1 = BT + (size_t)(n0 + (i1 >> 2)) * K + (i1 & 3) * 8;
  bf16_t* AsW0 = As + (size_t)(wave * 64) * 8;
  bf16_t* AsW1 = As + (size_t)(256 + wave * 64) * 8;
  bf16_t* BsW0 = Bs + (size_t)(wave * 64) * 8;
  bf16_t* BsW1 = Bs + (size_t)(256 + wave * 64) * 8;

  const int rsel = lane & 15;
  const int ksel = (lane >> 4) * 8;

  for (int k0 = 0; k0 < K; k0 += 32) {
    __syncthreads();
    load_lds16(Ag0 + k0, AsW0);
    load_lds16(Ag1 + k0, AsW1);
    load_lds16(Bg0 + k0, BsW0);
    load_lds16(Bg1 + k0, BsW1);
    __syncthreads();
    bf16x8 af[4], bfr[4];
#pragma unroll
    for (int i = 0; i < 4; ++i) {
      af[i]  = *(const bf16x8*)(As + (wm + i * 16 + rsel) * 32 + ksel);
      bfr[i] = *(const bf16x8*)(Bs + (wn + i * 16 + rsel) * 32 + ksel);
    }
#pragma unroll
    for (int mi = 0; mi < 4; ++mi)
#pragma unroll
      for (int ni = 0; ni < 4; ++ni)
        acc[mi][ni] = __builtin_amdgcn_mfma_f32_16x16x32_bf16(af[mi], bfr[ni], acc[mi][ni], 0, 0, 0);
  }

  const int row_l = (lane >> 4) * 4;
  const int col_l = lane & 15;
#pragma unroll
  for (int mi = 0; mi < 4; ++mi) {
#pragma unroll
    for (int ni = 0; ni < 4; ++ni) {
      const size_t base = (size_t)(m0 + wm + mi * 16 + row_l) * N + (size_t)(n0 + wn + ni * 16 + col_l);
#pragma unroll
      for (int r = 0; r < 4; ++r) {
        float vv = acc[mi][ni][r];
        if (mode == 0) {
          vv = fminf(8.0f, fmaxf(-8.0f, vv));
          ((_Float16*)outv)[base + (size_t)r * N] = (_Float16)vv;
        } else {
          ((float*)outv)[base + (size_t)r * N] = vv + resid[base + (size_t)r * N];
        }
      }
    }
  }
}

// ---------------- causal GQA flash attention, KVBLK=64, defer-max ----------------
// qkv f16 [4096][3072] (clipped; q-section roped IN-REGISTER here via tbl),
// K [B,8,S,64] (roped), Vt [B,8,64,S]  (all f16)
// Out bf16 [B*S, 2048] (row = b*2048+s, col = h*64+d)
// grid (32, KVH=8, B=2), block = 512 (8 waves = 4 GQA heads x 2 16-row tiles).
// Uniform 33 slots/block via (bx, 63-bx) chunk pairing. 3 LDS buffers, depth-2
// prefetch, counted vmcnt(2), ONE s_barrier per slot (stage for J+2 issued after
// barrier J targets buf[(J-1)%3] whose readers finished pre-barrier).
// Softmax: T13 defer-max (THR=8 log2 units); in-lane max only (v_max3 tree) in
// steady state; rare full-reduce+rescale path. Row-sum l via MFMA ones-operand.
#define STAGE_TO(J, SI) do { \
    _Float16* d_ = &KV[(SI)][ksel][wv4]; \
    const _Float16* s_ = gsrc + (size_t)(J) * gstep; \
    load_lds16(s_, d_); \
    load_lds16(s_ + 32, d_ + 2048); \
  } while (0)

#define ABODY(J, BI, SI) do { \
    const int j_ = (J); \
    if (j_ == nit - 1) asm volatile("s_waitcnt vmcnt(0)" ::: "memory"); \
    else               asm volatile("s_waitcnt vmcnt(2)" ::: "memory"); \
    __builtin_amdgcn_s_barrier(); \
    __builtin_amdgcn_sched_barrier(0); \
    if (j_ + 2 < nit) STAGE_TO(j_ + 2, SI); \
    const _Float16* Kbuf = &KV[(BI)][0][0]; \
    const _Float16* Vbuf = &KV[(BI)][1][0]; \
    f32x4 st[4] = {}; \
    __builtin_amdgcn_s_setprio(1); \
    _Pragma("unroll") \
    for (int mt_ = 0; mt_ < 4; ++mt_) { \
      const f16x8v kf0_ = *(const f16x8v*)(Kbuf + krowc[mt_]); \
      const f16x8v kf1_ = *(const f16x8v*)(Kbuf + 2048 + krowc[mt_]); \
      st[mt_] = __builtin_amdgcn_mfma_f32_16x16x32_f16(kf0_, qf0, st[mt_], 0, 0, 0); \
      st[mt_] = __builtin_amdgcn_mfma_f32_16x16x32_f16(kf1_, qf1, st[mt_], 0, 0, 0); \
    } \
    __builtin_amdgcn_s_setprio(0); \
    /* V frags now: independent of softmax, in flight during max/exp */ \
    f16x4v vA_[4], vB_[4], vC_[4], vD_[4]; \
    _Pragma("unroll") \
    for (int nt_ = 0; nt_ < 4; ++nt_) { \
      const _Float16* Vr_ = Vbuf + vrow[nt_]; \
      vA_[nt_] = *(const f16x4v*)(Vr_ + vca); \
      vB_[nt_] = *(const f16x4v*)(Vr_ + vcb); \
      vC_[nt_] = *(const f16x4v*)(Vr_ + 2048 + vca); \
      vD_[nt_] = *(const f16x4v*)(Vr_ + 2048 + vcb); \
    } \
    const int k0_ = j_ * 64; \
    if (k0_ + 64 > q0) { \
      _Pragma("unroll") \
      for (int mt_ = 0; mt_ < 4; ++mt_) \
        _Pragma("unroll") \
        for (int r_ = 0; r_ < 4; ++r_) { \
          if (k0_ + mt_ * 16 + lg * 4 + r_ > myq) st[mt_][r_] = -3.0e38f; \
        } \
    } \
    /* in-lane max (clang folds fmax triples to v_max3_f32) */ \
    const float x0_ = fmaxf(fmaxf(st[0][0], st[0][1]), st[0][2]); \
    const float x1_ = fmaxf(fmaxf(st[0][3], st[1][0]), st[1][1]); \
    const float x2_ = fmaxf(fmaxf(st[1][2], st[1][3]), st[2][0]); \
    const float x3_ = fmaxf(fmaxf(st[2][1], st[2][2]), st[2][3]); \
    const float x4_ = fmaxf(fmaxf(st[3][0], st[3][1]), st[3][2]); \
    float mx_ = fmaxf(fmaxf(fmaxf(x0_, x1_), fmaxf(x2_, x3_)), fmaxf(x4_, st[3][3])); \
    if (__any(mx_ > m_r + 8.0f)) {  /* rare: full reduce + rescale */ \
      mx_ = fmaxf(mx_, __shfl_xor(mx_, 16, 64)); \
      mx_ = fmaxf(mx_, __shfl_xor(mx_, 32, 64)); \
      const float mn_ = fmaxf(m_r, mx_); \
      const float al_ = exp2f(m_r - mn_); \
      _Pragma("unroll") \
      for (int r_ = 0; r_ < 4; ++r_) { \
        const float ao_ = __shfl(al_, lg * 4 + r_, 16); \
        ov[0][r_] *= ao_; ov[1][r_] *= ao_; ov[2][r_] *= ao_; ov[3][r_] *= ao_; \
        ovl[r_] *= ao_; \
      } \
      m_r = mn_; \
    } \
    f16x4v pf_[4]; \
    _Pragma("unroll") \
    for (int mt_ = 0; mt_ < 4; ++mt_) { \
      pf_[mt_] = pack4_f16(exp2f(st[mt_][0] - m_r), exp2f(st[mt_][1] - m_r), \
                           exp2f(st[mt_][2] - m_r), exp2f(st[mt_][3] - m_r)); \
    } \
    __builtin_amdgcn_s_setprio(1); \
    _Pragma("unroll") \
    for (int nt_ = 0; nt_ < 4; ++nt_) { \
      ov[nt_] = __builtin_amdgcn_mfma_f32_16x16x16f16(pf_[0], vA_[nt_], ov[nt_], 0, 0, 0); \
      ov[nt_] = __builtin_amdgcn_mfma_f32_16x16x16f16(pf_[1], vB_[nt_], ov[nt_], 0, 0, 0); \
      ov[nt_] = __builtin_amdgcn_mfma_f32_16x16x16f16(pf_[2], vC_[nt_], ov[nt_], 0, 0, 0); \
      ov[nt_] = __builtin_amdgcn_mfma_f32_16x16x16f16(pf_[3], vD_[nt_], ov[nt_], 0, 0, 0); \
    } \
    ovl = __builtin_amdgcn_mfma_f32_16x16x16f16(pf_[0], onesv, ovl, 0, 0, 0); \
    ovl = __builtin_amdgcn_mfma_f32_16x16x16f16(pf_[1], onesv, ovl, 0, 0, 0); \
    ovl = __builtin_amdgcn_mfma_f32_16x16x16f16(pf_[2], onesv, ovl, 0, 0, 0); \
    ovl = __builtin_amdgcn_mfma_f32_16x16x16f16(pf_[3], onesv, ovl, 0, 0, 0); \
    __builtin_amdgcn_s_setprio(0); \
  } while (0)

__global__ __launch_bounds__(512, 4) void attn_kernel(
    const _Float16* __restrict__ qkv, const int* __restrict__ pos,
    const float2* __restrict__ tbl,
    const _Float16* __restrict__ Kb, const _Float16* __restrict__ Vt,
    bf16_t* __restrict__ Out)
{
  __shared__ alignas(16) _Float16 KV[3][2][4096];  // [buf][K=0,V=1][2x 64x32 halves]

  const int kvh = blockIdx.y;
  const int b = blockIdx.z;
  const int t = threadIdx.x;
  const int lane = t & 63;
  const int wave = t >> 6;       // 0..7
  const int g = wave >> 1;       // q-head within GQA group
  const int tile = wave & 1;     // 16-row tile within the 32-row chunk
  const int h = kvh * 4 + g;
  const int ln15 = lane & 15;    // free-index lane (q for S^T / A; d for V / B)
  const int lg = lane >> 4;      // lane group (k-offset selector)

  const _Float16* Kh = Kb + ((size_t)(b * 8 + kvh) * 2048) * 64;
  const _Float16* Vh = Vt + ((size_t)(b * 8 + kvh) * 64) * 2048;

  // staging: threads 0-255 stage K (64kv x 64d), 256-511 stage V^T (64d x 64kv);
  // 2x 16B loads per thread per slot (row-halves 0-31 / 32-63).
  const bool stK = (t < 256);
  const int u = t & 255;
  const int srow = u >> 2;                             // kv for K, d for V
  const int scol = ((u & 3) ^ ((srow >> 1) & 3)) * 8;  // pre-swizzled source col
  const _Float16* gsrc = stK ? (Kh + (size_t)srow * 64 + scol)
                             : (Vh + (size_t)srow * 2048 + scol);
  const int gstep = stK ? 64 * 64 : 64;                // per-slot source advance
  const int ksel = stK ? 0 : 1;
  const int wv4 = (wave & 3) * 512;                    // wave-uniform LDS sub-base

  // compute-side swizzled LDS offsets (elements)
  const int svz = (ln15 >> 1) & 3;
  const int kc = (lg ^ svz) * 8;
  const int vca = ((lg >> 1) ^ svz) * 8 + (lg & 1) * 4;
  const int vcb = (((lg >> 1) + 2) ^ svz) * 8 + (lg & 1) * 4;
  int krowc[4], vrow[4];
#pragma unroll
  for (int i = 0; i < 4; ++i) {
    krowc[i] = (i * 16 + ln15) * 32 + kc;
    vrow[i] = (i * 16 + ln15) * 32;
  }
  const f16x4v onesv = {(_Float16)1.0f, (_Float16)1.0f, (_Float16)1.0f, (_Float16)1.0f};
  const float qsc = 0.125f * LOG2E;

  for (int half = 0; half < 2; ++half) {
    const int qc = (half == 0) ? blockIdx.x : (63 - blockIdx.x);
    const int q0 = qc * 32 + tile * 16;
    const int myq = q0 + ln15;
    const int nit = (qc >> 1) + 1;   // block-uniform slot count (64 keys/slot)

    // Q B-frags: n=ln15 (q row), k = lg*8+j (+32). Read the clipped qkv row
    // directly and apply neox rope + scale IN REGISTER (same f32 math and f16
    // rounding as the old rope kernel).
    const _Float16* qrow = qkv + (size_t)(b * 2048 + myq) * 3072 + h * 64;
    const float2* tq = tbl + (size_t)pos[b * 2048 + myq] * 32 + lg * 8;
    const f16x8v qr0 = *(const f16x8v*)(qrow + lg * 8);
    const f16x8v qr1 = *(const f16x8v*)(qrow + 32 + lg * 8);
    f16x8v qf0, qf1;
#pragma unroll
    for (int j = 0; j < 8; ++j) {
      const float2 cs = tq[j];
      const float x1 = (float)qr0[j], x2 = (float)qr1[j];
      qf0[j] = (_Float16)((x1 * cs.x - x2 * cs.y) * qsc);
      qf1[j] = (_Float16)((x2 * cs.x + x1 * cs.y) * qsc);
    }

    f32x4 ov[4] = {};     // O: rows q=lg*4+r, cols d=nt*16+ln15
    f32x4 ovl = {};       // l accumulator, same row layout (any col)
    float m_r = 0.0f;     // running max (log2 units), uniform across lg groups

    STAGE_TO(0, 0);
    if (nit > 1) STAGE_TO(1, 1);

    int it = 0;
    for (; it + 3 <= nit; it += 3) {
      ABODY(it, 0, 2);
      ABODY(it + 1, 1, 0);
      ABODY(it + 2, 2, 1);
    }
    // tail (<=2 slots; main loop exits at a multiple of 3, so buffers are 0,1;
    // tail slots never stage: j+2 >= nit always here)
    if (it < nit) { ABODY(it, 0, 2); ++it; }
    if (it < nit) { ABODY(it, 1, 0); }

    // epilogue: O rows q=lg*4+r; l lives in the same layout (no shuffles)
#pragma unroll
    for (int r = 0; r < 4; ++r) {
      const float ilo = 1.0f / ovl[r];
      const size_t obase = ((size_t)b * 2048 + (size_t)(q0 + lg * 4 + r)) * 2048 + (size_t)h * 64;
#pragma unroll
      for (int nt = 0; nt < 4; ++nt)
        Out[obase + nt * 16 + ln15] = (bf16_t)(ov[nt][r] * ilo);
    }
    // end-of-half fence: next half's prologue stages overwrite buffers 0,1
    __builtin_amdgcn_s_barrier();
    __builtin_amdgcn_sched_barrier(0);
  }
}
#undef ABODY
#undef STAGE_TO

// ---------------- launcher ----------------
extern "C" void kernel_launch(void* const* d_in, const int* in_sizes, int n_in,
                              void* d_out, int out_size, void* d_ws, size_t ws_size,
                              hipStream_t stream) {
  (void)in_sizes; (void)n_in; (void)out_size; (void)ws_size;
  const float* hid  = (const float*)d_in[0];
  const int*   pos  = (const int*)d_in[2];
  const float* ln1g = (const float*)d_in[4];
  const float* wqkv = (const float*)d_in[5];
  const float* wout = (const float*)d_in[6];
  const float* ln2g = (const float*)d_in[7];
  float* out = (float*)d_out;
  char* ws = (char*)d_ws;

  // workspace layout (bytes); peak ~88 MB
  bf16_t*   xb  = (bf16_t*)(ws + 0);          // 16.7MB x_bf16, later attn_bf16
  bf16_t*   wT  = (bf16_t*)(ws + 16777216);   // 12.6MB wqkvT
  _Float16* qkv = (_Float16*)(ws + 29360128); // 25.2MB qkv f16 (clipped)
  float2*   tbl = (float2*)(ws + 54525952);   // 0.5MB rope trig table
  bf16_t*   wOT = (bf16_t*)(ws + 55050240);   // 8.4MB woutT
  _Float16* kb  = (_Float16*)(ws + 79691776); // 4.2MB k (f16, roped)
  _Float16* vt  = (_Float16*)(ws + 83886080); // 4.2MB v^T (f16)  end 88080384

  // 1. LN1 + wqkv^T + wout^T + trig table (one launch, independent works)
  fused_pre<<<14592, 256, 0, stream>>>(hid, ln1g, xb, wqkv, wout, wT, wOT, tbl);
  // 2. qkv = clip(x @ w_qkv) -> f16
  gemm_bt<<<dim3(24, 32), 256, 0, stream>>>(xb, wT, 4096, 3072, 2048, 0, nullptr, qkv);
  // 3. k-rope -> kb + v -> vt [B,8,64,S] (one launch; q roped inside attn)
  kv_prep<<<2560, 256, 0, stream>>>(qkv, pos, tbl, kb, vt);
  // 4. attention -> xb (attn bf16 [4096][2048]; x dead)
  attn_kernel<<<dim3(32, 8, 2), 512, 0, stream>>>(qkv, pos, tbl, kb, vt, xb);
  // 5. residual2 = attn @ w_out + hid -> out[0:8388608]
  gemm_bt<<<dim3(16, 32), 256, 0, stream>>>(xb, wOT, 4096, 2048, 2048, 1, hid, out);
  // 6. LN2 -> out[8388608:16777216]
  ln_kernel<<<4096, 256, 0, stream>>>(out, ln2g, nullptr, out + 8388608);
}